// Round 15
// baseline (45.826 us; speedup 1.0000x reference)
//
#include <hip/hip_runtime.h>
#include <stdint.h>

#define MROWS 131072
#define NSPEC 8
#define DIN   128
#define NOUT  256
#define BM    192                    // 48KB LDS -> 3 blocks/CU (12 waves), vs R10's 2
#define NSUB  (BM / 16)              // 12 subtiles
#define NBLK  ((MROWS + BM - 1) / BM)   // 683 (last block: 128 valid rows)

typedef __attribute__((ext_vector_type(8))) short s16x8;
typedef __attribute__((ext_vector_type(4))) float f32x4;

// workspace: only the bf16 fragment-ordered W
#define OFF_BF    ((size_t)0)        // 8*16*4*1024 = 524288 B
#define WS_NEEDED ((size_t)524288)

__device__ __forceinline__ uint32_t bf16_1(float f) {
  union { float f; uint32_t u; } v; v.f = f;
  return (v.u + 0x7FFFu + ((v.u >> 16) & 1u)) >> 16;  // RNE, inputs finite
}

// Convert W [8][128][256] fp32 -> bf16 fragment order (R10 col-interleaved
// mapping): chunk c = ((s*16 + f)*4 + kt), f = w*4 + ni;
// n = (f>>2)*64 + (l&15)*4 + (f&3); lane l holds B[k = kt*32+(l>>4)*8+j][n].
__global__ void k_convert(const float* __restrict__ B, char* __restrict__ ws) {
  int gid = blockIdx.x * 256 + threadIdx.x;   // 32768 threads
  int l  = gid & 63;
  int c  = gid >> 6;                          // 0..511
  int kt = c & 3;
  int f  = (c >> 2) & 15;
  int s  = c >> 6;
  int n  = (f >> 2) * 64 + (l & 15) * 4 + (f & 3);
  int k0 = kt * 32 + (l >> 4) * 8;
  const float* src = B + (size_t)s * DIN * NOUT + n;
  uint32_t w0 = bf16_1(src[(size_t)(k0 + 0) * NOUT]) | (bf16_1(src[(size_t)(k0 + 1) * NOUT]) << 16);
  uint32_t w1 = bf16_1(src[(size_t)(k0 + 2) * NOUT]) | (bf16_1(src[(size_t)(k0 + 3) * NOUT]) << 16);
  uint32_t w2 = bf16_1(src[(size_t)(k0 + 4) * NOUT]) | (bf16_1(src[(size_t)(k0 + 5) * NOUT]) << 16);
  uint32_t w3 = bf16_1(src[(size_t)(k0 + 6) * NOUT]) | (bf16_1(src[(size_t)(k0 + 7) * NOUT]) << 16);
  *(uint4*)(ws + OFF_BF + (size_t)c * 1024 + (size_t)l * 16) = make_uint4(w0, w1, w2, w3);
}

// Grouped GEMM, R10 structure with BM=192: block-local counting sort,
// sequential A stage into XOR-swizzled LDS, per-species MFMA over slot
// ranges, predicated float4 stores. 3 independent blocks/CU.
__global__ __launch_bounds__(256, 3) void k_gemm_ns(const float* __restrict__ A,
                                                    const int* __restrict__ sp,
                                                    const char* __restrict__ ws,
                                                    float* __restrict__ out) {
  const char* Bf = ws + OFF_BF;
  __shared__ char As[BM * 256];     // 48 KB: [slot][128 k] bf16, XOR-swizzled
  __shared__ int slotOf[BM];        // natural row (in-block) -> slot
  __shared__ int invOf[BM];         // slot -> natural row (in-block)
  __shared__ int cnt[NSPEC];
  __shared__ int gstart[NSPEC + 1];

  int t = threadIdx.x;
  int base = blockIdx.x * BM;

  // ---- block-local counting sort of BM rows by species (threads 0..BM-1)
  // rows past MROWS (last block only) are binned as species 7; their stage
  // loads read zeros and their stores are guarded out below.
  if (t < NSPEC) cnt[t] = 0;
  __syncthreads();
  if (t < BM) {
    int valid = (base + t) < MROWS;
    int s_r = valid ? (sp[base + t] & 7) : 7;
    int rank = atomicAdd(&cnt[s_r], 1);
    slotOf[t] = rank;                         // temp: rank within species
  }
  __syncthreads();
  if (t == 0) {
    int a = 0;
    #pragma unroll
    for (int j = 0; j < NSPEC; ++j) { gstart[j] = a; a += cnt[j]; }
    gstart[NSPEC] = a;                        // == BM
  }
  __syncthreads();
  if (t < BM) {
    int valid = (base + t) < MROWS;
    int s_r = valid ? (sp[base + t] & 7) : 7;
    int myslot = gstart[s_r] + slotOf[t];
    slotOf[t] = myslot;
    invOf[myslot] = t;
  }
  __syncthreads();

  // ---- stage A: SEQUENTIAL global reads, LDS write at sorted slot
  int f4 = t & 31, r0 = t >> 5;               // 8 rows per iteration, 24 iters
  #pragma unroll
  for (int it = 0; it < BM / 8; ++it) {
    int r = r0 + it * 8;
    float4 v = make_float4(0.f, 0.f, 0.f, 0.f);
    if (base + r < MROWS)
      v = *(const float4*)(A + (size_t)(base + r) * DIN + f4 * 4);
    int sl = slotOf[r];                       // broadcast within 32-lane group
    uint32_t lo = bf16_1(v.x) | (bf16_1(v.y) << 16);
    uint32_t hi = bf16_1(v.z) | (bf16_1(v.w) << 16);
    int off = (sl * 256 + f4 * 8) ^ ((sl & 7) << 4);   // G4 swizzle
    *(uint2*)(As + off) = make_uint2(lo, hi);
  }
  __syncthreads();

  // ---- per-species MFMA over slot ranges (wave w: cols w*64 .. w*64+63)
  int w = t >> 6, l = t & 63;
  int colBase = w * 64 + (l & 15) * 4;        // col-interleaved layout
  for (int s = 0; s < NSPEC; ++s) {
    int gs = gstart[s], ge = gstart[s + 1];
    if (gs == ge) continue;
    // B fragments for this species & this wave's 64-col strip: 16 x 1KB from L2
    s16x8 bfr[4][4];                          // [ni][kt] -> 64 VGPR
    #pragma unroll
    for (int ni = 0; ni < 4; ++ni)
      #pragma unroll
      for (int kt = 0; kt < 4; ++kt) {
        int c = (s * 16 + (w * 4 + ni)) * 4 + kt;
        bfr[ni][kt] = *(const s16x8*)(Bf + (size_t)c * 1024 + (size_t)l * 16);
      }
    int st0 = gs >> 4, st1 = (ge - 1) >> 4;   // subtiles touching this group
    for (int st = st0; st <= st1; ++st) {
      f32x4 acc[4];
      #pragma unroll
      for (int ni = 0; ni < 4; ++ni) acc[ni] = (f32x4){0.f, 0.f, 0.f, 0.f};
      #pragma unroll
      for (int kt = 0; kt < 4; ++kt) {
        int r = st * 16 + (l & 15);
        int off = (r * 256 + kt * 64 + (l >> 4) * 16) ^ ((r & 7) << 4);
        s16x8 afr = *(const s16x8*)(As + off);
        #pragma unroll
        for (int ni = 0; ni < 4; ++ni)
          acc[ni] = __builtin_amdgcn_mfma_f32_16x16x32_bf16(afr, bfr[ni][kt], acc[ni], 0, 0, 0);
      }
      // predicated float4 store: lane's 4 ni-values are consecutive cols
      #pragma unroll
      for (int q = 0; q < 4; ++q) {
        int slotrow = st * 16 + ((l >> 4) << 2) + q;
        if (slotrow >= gs && slotrow < ge) {
          int rid = base + invOf[slotrow];    // broadcast within 16-lane group
          if (rid < MROWS) {
            float4 v4 = make_float4(acc[0][q], acc[1][q], acc[2][q], acc[3][q]);
            *(float4*)(out + (size_t)rid * NOUT + colBase) = v4;
          }
        }
      }
    }
  }
}

// ws-free correctness fallback (only if ws_size is unexpectedly small)
__global__ void k_naive(const float* __restrict__ A, const int* __restrict__ sp,
                        const float* __restrict__ B, float* __restrict__ out) {
  __shared__ float av[DIN];
  int m = blockIdx.x;
  int n = threadIdx.x;
  if (n < DIN) av[n] = A[(size_t)m * DIN + n];
  __syncthreads();
  int s = sp[m] & 7;
  const float* b = B + (size_t)s * DIN * NOUT + n;
  float acc = 0.f;
  #pragma unroll 8
  for (int k = 0; k < DIN; ++k) acc = fmaf(av[k], b[(size_t)k * NOUT], acc);
  out[(size_t)m * NOUT + n] = acc;
}

extern "C" void kernel_launch(void* const* d_in, const int* in_sizes, int n_in,
                              void* d_out, int out_size, void* d_ws, size_t ws_size,
                              hipStream_t stream) {
  const float* values = (const float*)d_in[0];
  const int*   sp     = (const int*)d_in[1];
  const float* B      = (const float*)d_in[2];
  float*       out    = (float*)d_out;

  if (d_ws == nullptr || ws_size < WS_NEEDED) {
    k_naive<<<MROWS, NOUT, 0, stream>>>(values, sp, B, out);
    return;
  }
  char* ws = (char*)d_ws;
  k_convert<<<128, 256, 0, stream>>>(B, ws);
  k_gemm_ns<<<NBLK, 256, 0, stream>>>(values, sp, ws, out);
}

// Round 16
// 42.594 us; speedup vs baseline: 1.0759x; 1.0759x over previous
//
#include <hip/hip_runtime.h>
#include <stdint.h>

#define MROWS 131072
#define NSPEC 8
#define DIN   128
#define NOUT  256
#define BM    256                    // natural rows per block (block-local sort)

typedef __attribute__((ext_vector_type(8))) short s16x8;
typedef __attribute__((ext_vector_type(4))) float f32x4;

// workspace: only the bf16 fragment-ordered W
#define OFF_BF    ((size_t)0)        // 8*16*4*1024 = 524288 B
#define WS_NEEDED ((size_t)524288)

__device__ __forceinline__ uint32_t bf16_1(float f) {
  union { float f; uint32_t u; } v; v.f = f;
  return (v.u + 0x7FFFu + ((v.u >> 16) & 1u)) >> 16;  // RNE, inputs finite
}

// Convert W [8][128][256] fp32 -> bf16 fragment order.
// chunk c = ((s*16 + f)*4 + kt); lane l holds
// B[k = kt*32 + (l>>4)*8 + j][n], j=0..7.
// COLUMN-INTERLEAVED mapping: f = w*4 + ni  ->  n = w*64 + (l&15)*4 + ni
// so that D-tile ni, lane m covers global col w*64 + m*4 + ni; a lane's four
// ni-values are then 4 CONSECUTIVE floats -> float4 epilogue stores.
__global__ void k_convert(const float* __restrict__ B, char* __restrict__ ws) {
  int gid = blockIdx.x * 256 + threadIdx.x;   // 32768 threads
  int l  = gid & 63;
  int c  = gid >> 6;                          // 0..511
  int kt = c & 3;
  int f  = (c >> 2) & 15;
  int s  = c >> 6;
  int n  = (f >> 2) * 64 + (l & 15) * 4 + (f & 3);
  int k0 = kt * 32 + (l >> 4) * 8;
  const float* src = B + (size_t)s * DIN * NOUT + n;
  uint32_t w0 = bf16_1(src[(size_t)(k0 + 0) * NOUT]) | (bf16_1(src[(size_t)(k0 + 1) * NOUT]) << 16);
  uint32_t w1 = bf16_1(src[(size_t)(k0 + 2) * NOUT]) | (bf16_1(src[(size_t)(k0 + 3) * NOUT]) << 16);
  uint32_t w2 = bf16_1(src[(size_t)(k0 + 4) * NOUT]) | (bf16_1(src[(size_t)(k0 + 5) * NOUT]) << 16);
  uint32_t w3 = bf16_1(src[(size_t)(k0 + 6) * NOUT]) | (bf16_1(src[(size_t)(k0 + 7) * NOUT]) << 16);
  *(uint4*)(ws + OFF_BF + (size_t)c * 1024 + (size_t)l * 16) = make_uint4(w0, w1, w2, w3);
}

// Sort-free grouped GEMM: one block = 256 NATURAL rows x 256 cols, 4 waves.
// Block-local counting sort into LDS slots; per species: B-frags in regs,
// MFMA over the species' slot range; boundary subtiles recomputed per species
// with predicated float4 stores.
__global__ __launch_bounds__(256, 2) void k_gemm_ns(const float* __restrict__ A,
                                                    const int* __restrict__ sp,
                                                    const char* __restrict__ ws,
                                                    float* __restrict__ out) {
  const char* Bf = ws + OFF_BF;
  __shared__ char As[BM * 256];     // 64 KB: [slot][128 k] bf16, XOR-swizzled
  __shared__ int slotOf[BM];        // natural row (in-block) -> slot
  __shared__ int invOf[BM];         // slot -> natural row (in-block)
  __shared__ int cnt[NSPEC];
  __shared__ int gstart[NSPEC + 1];

  int t = threadIdx.x;
  int base = blockIdx.x * BM;

  // ---- block-local counting sort of 256 rows by species
  if (t < NSPEC) cnt[t] = 0;
  __syncthreads();
  int s_r = sp[base + t] & 7;                 // thread t owns natural row t
  int rank = atomicAdd(&cnt[s_r], 1);
  __syncthreads();
  if (t == 0) {
    int a = 0;
    #pragma unroll
    for (int j = 0; j < NSPEC; ++j) { gstart[j] = a; a += cnt[j]; }
    gstart[NSPEC] = a;                        // == BM
  }
  __syncthreads();
  int myslot = gstart[s_r] + rank;
  slotOf[t] = myslot;
  invOf[myslot] = t;
  __syncthreads();

  // ---- stage A: SEQUENTIAL global reads, LDS write at sorted slot
  int f4 = t & 31, r0 = t >> 5;               // 8 rows per iteration
  #pragma unroll
  for (int it = 0; it < 32; ++it) {
    int r = r0 + it * 8;
    float4 v = *(const float4*)(A + (size_t)(base + r) * DIN + f4 * 4);
    int sl = slotOf[r];                       // broadcast within 32-lane group
    uint32_t lo = bf16_1(v.x) | (bf16_1(v.y) << 16);
    uint32_t hi = bf16_1(v.z) | (bf16_1(v.w) << 16);
    int off = (sl * 256 + f4 * 8) ^ ((sl & 7) << 4);   // G4 swizzle
    *(uint2*)(As + off) = make_uint2(lo, hi);
  }
  __syncthreads();

  // ---- per-species MFMA over slot ranges
  int w = t >> 6, l = t & 63;
  int colBase = w * 64 + (l & 15) * 4;        // col-interleaved layout
  for (int s = 0; s < NSPEC; ++s) {
    int gs = gstart[s], ge = gstart[s + 1];
    if (gs == ge) continue;
    // B fragments for this species & this wave's 64-col strip: 16 x 1KB from L2
    s16x8 bfr[4][4];                          // [ni][kt], fully unrolled -> regs
    #pragma unroll
    for (int ni = 0; ni < 4; ++ni)
      #pragma unroll
      for (int kt = 0; kt < 4; ++kt) {
        int c = (s * 16 + (w * 4 + ni)) * 4 + kt;
        bfr[ni][kt] = *(const s16x8*)(Bf + (size_t)c * 1024 + (size_t)l * 16);
      }
    int st0 = gs >> 4, st1 = (ge - 1) >> 4;   // subtiles touching this group
    for (int st = st0; st <= st1; ++st) {
      f32x4 acc[4];
      #pragma unroll
      for (int ni = 0; ni < 4; ++ni) acc[ni] = (f32x4){0.f, 0.f, 0.f, 0.f};
      #pragma unroll
      for (int kt = 0; kt < 4; ++kt) {
        int r = st * 16 + (l & 15);
        int off = (r * 256 + kt * 64 + (l >> 4) * 16) ^ ((r & 7) << 4);
        s16x8 afr = *(const s16x8*)(As + off);
        #pragma unroll
        for (int ni = 0; ni < 4; ++ni)
          acc[ni] = __builtin_amdgcn_mfma_f32_16x16x32_bf16(afr, bfr[ni][kt], acc[ni], 0, 0, 0);
      }
      // predicated float4 store: lane's 4 ni-values are consecutive cols
      #pragma unroll
      for (int q = 0; q < 4; ++q) {
        int slotrow = st * 16 + ((l >> 4) << 2) + q;
        if (slotrow >= gs && slotrow < ge) {
          int rid = base + invOf[slotrow];    // broadcast within 16-lane group
          float4 v4 = make_float4(acc[0][q], acc[1][q], acc[2][q], acc[3][q]);
          *(float4*)(out + (size_t)rid * NOUT + colBase) = v4;
        }
      }
    }
  }
}

// ws-free correctness fallback (only if ws_size is unexpectedly small)
__global__ void k_naive(const float* __restrict__ A, const int* __restrict__ sp,
                        const float* __restrict__ B, float* __restrict__ out) {
  __shared__ float av[DIN];
  int m = blockIdx.x;
  int n = threadIdx.x;
  if (n < DIN) av[n] = A[(size_t)m * DIN + n];
  __syncthreads();
  int s = sp[m] & 7;
  const float* b = B + (size_t)s * DIN * NOUT + n;
  float acc = 0.f;
  #pragma unroll 8
  for (int k = 0; k < DIN; ++k) acc = fmaf(av[k], b[(size_t)k * NOUT], acc);
  out[(size_t)m * NOUT + n] = acc;
}

extern "C" void kernel_launch(void* const* d_in, const int* in_sizes, int n_in,
                              void* d_out, int out_size, void* d_ws, size_t ws_size,
                              hipStream_t stream) {
  const float* values = (const float*)d_in[0];
  const int*   sp     = (const int*)d_in[1];
  const float* B      = (const float*)d_in[2];
  float*       out    = (float*)d_out;

  if (d_ws == nullptr || ws_size < WS_NEEDED) {
    k_naive<<<MROWS, NOUT, 0, stream>>>(values, sp, B, out);
    return;
  }
  char* ws = (char*)d_ws;
  k_convert<<<128, 256, 0, stream>>>(B, ws);
  k_gemm_ns<<<MROWS / BM, 256, 0, stream>>>(values, sp, ws, out);
}